// Round 5
// baseline (48.446 us; speedup 1.0000x reference)
//
#include <hip/hip_runtime.h>

#define Nn 4096
#define NTRI 528              // 32*33/2 upper-tri 128x128 tiles
#define NBLK 2080             // 2*528 + 1024

typedef __attribute__((ext_vector_type(8))) short  short8v;
typedef __attribute__((ext_vector_type(4))) float  f32x4;

#define C_K   0.7213475204444817f   // log2(e)/mu, mu=2
#define C_2K  1.4426950408889634f   // 2*log2(e)/mu
#define SKIP_BOUND -40.0f           // exp2(-40)*16.7M*beta ~ 1e-19 << 1e-5 threshold

__device__ __forceinline__ unsigned short f2bf(float f) {
  unsigned u = __float_as_uint(f);
  u += 0x7fffu + ((u >> 16) & 1u);   // round-to-nearest-even
  return (unsigned short)(u >> 16);
}

// ---- prep: bf16 cast + prescaled norms kn[row] = -K * ||row||^2 -------------
__global__ __launch_bounds__(256) void prep_kernel(const float* __restrict__ X,
                                                   const float* __restrict__ Y,
                                                   float* __restrict__ kn,
                                                   unsigned short* __restrict__ Xb,
                                                   unsigned short* __restrict__ Yb) {
  int wave = threadIdx.x >> 6;
  int lane = threadIdx.x & 63;
  int row = blockIdx.x * 4 + wave;            // 0..8191
  const float* src;
  unsigned short* dst;
  if (row < Nn) { src = X + (size_t)row * 128;        dst = Xb + (size_t)row * 128; }
  else          { src = Y + (size_t)(row - Nn) * 128; dst = Yb + (size_t)(row - Nn) * 128; }
  float2 v = reinterpret_cast<const float2*>(src)[lane];
  float s = v.x * v.x + v.y * v.y;
#pragma unroll
  for (int off = 32; off > 0; off >>= 1) s += __shfl_xor(s, off);
  ushort2 h;
  h.x = f2bf(v.x);
  h.y = f2bf(v.y);
  reinterpret_cast<ushort2*>(dst)[lane] = h;
  if (lane == 0) kn[row] = -C_K * s;
}

// ---- fused pairwise-exp-sum: LDS-free, direct global->VGPR fragments --------
// t < 528:        q=0 (XX), upper-tri tile (by<=bx), off-diag weight 2
// 528 <= t <1056: q=1 (YY), same
// t >= 1056:      q=2 (XY), full 32x32
//
// MFMA 16x16x32 A/B fragment = (row = lane&15, k-bytes [ (lane>>4)*16, +16 ))
// which is 16 contiguous bytes of the row-major bf16 matrix -> load straight
// from global (L2-resident, 2MB total). No LDS, no barriers in the hot path.
__global__ __launch_bounds__(256, 4) void mmd_main(const unsigned short* __restrict__ Xb,
                                                   const unsigned short* __restrict__ Yb,
                                                   const float* __restrict__ kn,
                                                   float* __restrict__ partials) {
  __shared__ float red[4];

  const int t = blockIdx.x;
  int q, bx, by;
  if (t < 2 * NTRI) {
    q = (t >= NTRI) ? 1 : 0;
    const int u = t - q * NTRI;
    int r = (int)((sqrtf(8.f * (float)u + 1.f) - 1.f) * 0.5f);
    while ((r + 1) * (r + 2) / 2 <= u) ++r;
    while (r * (r + 1) / 2 > u) --r;
    bx = r; by = u - r * (r + 1) / 2;          // by <= bx
  } else {
    q = 2;
    const int u = t - 2 * NTRI;
    by = u >> 5; bx = u & 31;
  }

  const unsigned short* Asrc = (q == 1) ? Yb : Xb;
  const unsigned short* Bsrc = (q == 0) ? Xb : Yb;
  const float* knA = (q == 1) ? kn + Nn : kn;
  const float* knB = (q == 0) ? kn : kn + Nn;
  const int R0 = by << 7, C0 = bx << 7;

  const int lane = threadIdx.x & 63;
  const int wv   = threadIdx.x >> 6;
  const int wr = wv >> 1, wc = wv & 1;    // 2x2 wave grid, 64x64 per wave
  const int lr = lane & 15, kq = lane >> 4;

  // per-lane fragment base addresses (row-major, 256 B per row)
  const char* Abase = (const char*)Asrc + (((size_t)(R0 + (wr << 6) + lr)) << 8) + (kq << 4);
  const char* Bbase = (const char*)Bsrc + (((size_t)(C0 + (wc << 6) + lr)) << 8) + (kq << 4);

  f32x4 acc[4][4];
#pragma unroll
  for (int m = 0; m < 4; ++m)
#pragma unroll
    for (int n = 0; n < 4; ++n)
      acc[m][n] = (f32x4){0.f, 0.f, 0.f, 0.f};

#pragma unroll
  for (int ks = 0; ks < 4; ++ks) {
    short8v a[4], b[4];
#pragma unroll
    for (int m = 0; m < 4; ++m)          // m*16 rows = m*4096 B; k-step = ks*64 B
      a[m] = *reinterpret_cast<const short8v*>(Abase + (m << 12) + (ks << 6));
#pragma unroll
    for (int n = 0; n < 4; ++n)
      b[n] = *reinterpret_cast<const short8v*>(Bbase + (n << 12) + (ks << 6));
#pragma unroll
    for (int m = 0; m < 4; ++m)
#pragma unroll
      for (int n = 0; n < 4; ++n)
        acc[m][n] = __builtin_amdgcn_mfma_f32_16x16x32_bf16(a[m], b[n], acc[m][n], 0, 0, 0);
  }

  // ---- epilogue ---------------------------------------------------------------
  const bool diagblk = (q < 2) && (bx == by);
  f32x4 ax[4];
  float cy[4];
#pragma unroll
  for (int m = 0; m < 4; ++m)
    ax[m] = *reinterpret_cast<const f32x4*>(knA + R0 + (wr << 6) + (m << 4) + (kq << 2));
#pragma unroll
  for (int n = 0; n < 4; ++n)
    cy[n] = knB[C0 + (wc << 6) + (n << 4) + lr];

  // wave-level skip: upper-bound max exponent arg; 4 parallel fmax chains
  f32x4 vm = acc[0][0];
#pragma unroll
  for (int m = 0; m < 4; ++m)
#pragma unroll
    for (int n = 0; n < 4; ++n) {
      if (m == 0 && n == 0) continue;
      vm[0] = fmaxf(vm[0], acc[m][n][0]);
      vm[1] = fmaxf(vm[1], acc[m][n][1]);
      vm[2] = fmaxf(vm[2], acc[m][n][2]);
      vm[3] = fmaxf(vm[3], acc[m][n][3]);
    }
  float amax = fmaxf(fmaxf(vm[0], vm[1]), fmaxf(vm[2], vm[3]));
  float axm = -1e30f;
#pragma unroll
  for (int m = 0; m < 4; ++m)
    axm = fmaxf(axm, fmaxf(fmaxf(ax[m][0], ax[m][1]), fmaxf(ax[m][2], ax[m][3])));
  float cym = fmaxf(fmaxf(cy[0], cy[1]), fmaxf(cy[2], cy[3]));
  float bound = fmaf(amax, C_2K, axm + cym);

  float local = 0.f;
  if (__any(bound > SKIP_BOUND)) {
    float l0 = 0.f, l1 = 0.f, l2 = 0.f, l3 = 0.f;
#pragma unroll
    for (int m = 0; m < 4; ++m) {
      const int rbase = (wr << 6) + (m << 4) + (kq << 2);
#pragma unroll
      for (int n = 0; n < 4; ++n) {
        const float e0 = __builtin_amdgcn_exp2f(fmaf(acc[m][n][0], C_2K, ax[m][0] + cy[n]));
        const float e1 = __builtin_amdgcn_exp2f(fmaf(acc[m][n][1], C_2K, ax[m][1] + cy[n]));
        const float e2 = __builtin_amdgcn_exp2f(fmaf(acc[m][n][2], C_2K, ax[m][2] + cy[n]));
        const float e3 = __builtin_amdgcn_exp2f(fmaf(acc[m][n][3], C_2K, ax[m][3] + cy[n]));
        if (diagblk) {
          const int cc = (wc << 6) + (n << 4) + lr;
          if (rbase + 0 != cc) l0 += e0;
          if (rbase + 1 != cc) l1 += e1;
          if (rbase + 2 != cc) l2 += e2;
          if (rbase + 3 != cc) l3 += e3;
        } else {
          l0 += e0; l1 += e1; l2 += e2; l3 += e3;
        }
      }
    }
    local = (l0 + l1) + (l2 + l3);
#pragma unroll
    for (int off = 32; off > 0; off >>= 1) local += __shfl_xor(local, off);
  }

  if (lane == 0) red[wv] = local;
  __syncthreads();
  if (threadIdx.x == 0) {
    float s = (red[0] + red[1]) + (red[2] + red[3]);
    float w;
    if (q < 2) w = ((bx == by) ? 1.f : 2.f) * (1.0f / 16773120.0f);  // alpha
    else       w = -2.0f / 16777216.0f;                               // -2*beta
    partials[t] = s * w;
  }
}

// ---- deterministic final reduction ------------------------------------------
__global__ __launch_bounds__(256) void mmd_final(const float* __restrict__ partials,
                                                 float* __restrict__ out) {
  float v = 0.f;
  for (int i = threadIdx.x; i < NBLK; i += 256) v += partials[i];
#pragma unroll
  for (int off = 32; off > 0; off >>= 1) v += __shfl_xor(v, off);
  __shared__ float red[4];
  if ((threadIdx.x & 63) == 0) red[threadIdx.x >> 6] = v;
  __syncthreads();
  if (threadIdx.x == 0) {
    // analytic diagonal: n*(alpha1+alpha2) = 2/4095
    out[0] = ((red[0] + red[1]) + (red[2] + red[3])) + (float)(2.0 / 4095.0);
  }
}

extern "C" void kernel_launch(void* const* d_in, const int* in_sizes, int n_in,
                              void* d_out, int out_size, void* d_ws, size_t ws_size,
                              hipStream_t stream) {
  const float* X = (const float*)d_in[0];
  const float* Y = (const float*)d_in[1];
  float* kn       = (float*)d_ws;                       // 8192 floats (-K*norm^2)
  float* partials = kn + 8192;                          // 2080 floats
  unsigned short* Xb = (unsigned short*)(partials + 2080);
  unsigned short* Yb = Xb + (size_t)Nn * 128;
  float* out = (float*)d_out;

  hipLaunchKernelGGL(prep_kernel, dim3(2048), dim3(256), 0, stream, X, Y, kn, Xb, Yb);
  hipLaunchKernelGGL(mmd_main, dim3(NBLK), dim3(256), 0, stream, Xb, Yb, kn, partials);
  hipLaunchKernelGGL(mmd_final, dim3(1), dim3(256), 0, stream, partials, out);
}

// Round 6
// 22.465 us; speedup vs baseline: 2.1565x; 2.1565x over previous
//
#include <hip/hip_runtime.h>

#define Nn 4096
#define NTRI 528              // 32*33/2 upper-tri 128x128 tiles
#define NBLK 2080             // 2*528 + 1024

typedef __attribute__((ext_vector_type(4))) float f32x4;

#define C_K   0.7213475204444817f   // log2(e)/mu, mu=2
#define C_2K  1.4426950408889634f   // 2*log2(e)/mu
#define SKIP_BOUND -40.0f           // exp2(-40)*16.7M*beta ~ 1e-19 << 1e-5 threshold

// manual f32 -> fp8 e4m3fn (RNE, FTZ below 2^-6, saturate to 448)
__device__ __forceinline__ unsigned int f2e4m3(float f) {
  unsigned u = __float_as_uint(f);
  unsigned s = (u >> 24) & 0x80u;
  int e = (int)((u >> 23) & 0xff);
  unsigned m = u & 0x7fffffu;
  if (e < 121) return s;                         // FTZ (|x| < 2^-6), incl. zero
  unsigned mr = m + 0x7ffffu + ((m >> 20) & 1u); // RNE to 3 mantissa bits
  if (mr & 0x800000u) { mr = 0; e += 1; }
  int code = ((e - 120) << 3) | (int)(mr >> 20);
  if (code > 0x7e) code = 0x7e;                  // clamp to 448 (no inf/nan)
  return s | (unsigned)code;
}

__device__ __forceinline__ void gload_lds16(const void* g, void* l) {
  __builtin_amdgcn_global_load_lds(
      (const __attribute__((address_space(1))) unsigned int*)g,
      (__attribute__((address_space(3))) unsigned int*)l, 16, 0, 0);
}

// ---- prep: fp8 cast + prescaled norms kn[row] = -K * ||row||^2 --------------
// rows 0..4095 = X, 4096..8191 = Y
__global__ __launch_bounds__(256) void prep_kernel(const float* __restrict__ X,
                                                   const float* __restrict__ Y,
                                                   float* __restrict__ kn,
                                                   unsigned char* __restrict__ Xq,
                                                   unsigned char* __restrict__ Yq) {
  int wave = threadIdx.x >> 6;
  int lane = threadIdx.x & 63;
  int row = blockIdx.x * 4 + wave;            // 0..8191
  const float* src;
  unsigned char* dst;
  if (row < Nn) { src = X + (size_t)row * 128;        dst = Xq + (size_t)row * 128; }
  else          { src = Y + (size_t)(row - Nn) * 128; dst = Yq + (size_t)(row - Nn) * 128; }
  float2 v = reinterpret_cast<const float2*>(src)[lane];
  float s = v.x * v.x + v.y * v.y;
#pragma unroll
  for (int off = 32; off > 0; off >>= 1) s += __shfl_xor(s, off);
  unsigned short h = (unsigned short)(f2e4m3(v.x) | (f2e4m3(v.y) << 8));
  reinterpret_cast<unsigned short*>(dst)[lane] = h;
  if (lane == 0) kn[row] = -C_K * s;
}

// ---- fused pairwise-exp-sum: fp8 MFMA, single-stage LDS, one barrier ---------
// t < 528:        q=0 (XX), upper-tri tile (by<=bx), off-diag weight 2
// 528 <= t <1056: q=1 (YY), same
// t >= 1056:      q=2 (XY), full 32x32
//
// LDS tile per operand: [128 rows][128 B fp8], row = 8 x 16B units.
// Swizzle: logical (row r, unit u) stored at physical unit p = u ^ (r&7).
// DMA: each gload_lds16 covers one 8-row/1KB group, lane l -> (row l>>3,
// unit (l&7)^((l>>3)&7)) -> global source is a PERMUTATION of a contiguous
// 1KB span (16 consecutive cache lines -> coalesced), LDS dest linear.
// Read: ds_read_b64, 64 lanes x 8B = 512B = 4-phase minimum; swizzle puts
// exactly 4 lanes per bank -> zero excess conflict.
__global__ __launch_bounds__(256, 4) void mmd_main(const unsigned char* __restrict__ Xq,
                                                   const unsigned char* __restrict__ Yq,
                                                   const float* __restrict__ kn,
                                                   float* __restrict__ partials) {
  __shared__ __align__(16) char As[128 * 128];
  __shared__ __align__(16) char Bs[128 * 128];
  __shared__ float red[4];

  const int t = blockIdx.x;
  int q, bx, by;
  if (t < 2 * NTRI) {
    q = (t >= NTRI) ? 1 : 0;
    const int u = t - q * NTRI;
    int r = (int)((sqrtf(8.f * (float)u + 1.f) - 1.f) * 0.5f);
    while ((r + 1) * (r + 2) / 2 <= u) ++r;
    while (r * (r + 1) / 2 > u) --r;
    bx = r; by = u - r * (r + 1) / 2;          // by <= bx
  } else {
    q = 2;
    const int u = t - 2 * NTRI;
    by = u >> 5; bx = u & 31;
  }

  const unsigned char* Asrc = (q == 1) ? Yq : Xq;
  const unsigned char* Bsrc = (q == 0) ? Xq : Yq;
  const float* knA = (q == 1) ? kn + Nn : kn;
  const float* knB = (q == 0) ? kn : kn + Nn;
  const int R0 = by << 7, C0 = bx << 7;

  const int lane = threadIdx.x & 63;
  const int wv   = threadIdx.x >> 6;
  const int wr = wv >> 1, wc = wv & 1;    // 2x2 wave grid, 64x64 per wave
  const int lr = lane & 15, kq = lane >> 4;

  // ---- stage: 4+4 gload_lds16 per wave, one 8-row group each ----------------
  {
    const int rg = lane >> 3;                      // row within 8-row group
    const int uu = (lane & 7) ^ (rg & 7);          // logical unit for this slot
    const char* Ag = (const char*)Asrc + ((size_t)(R0 + (wv << 5) + rg) << 7) + (uu << 4);
    const char* Bg = (const char*)Bsrc + ((size_t)(C0 + (wv << 5) + rg) << 7) + (uu << 4);
#pragma unroll
    for (int i = 0; i < 4; ++i) {                  // 4 groups = 32 rows per wave
      gload_lds16(Ag + (i << 10), As + (wv << 12) + (i << 10));
      gload_lds16(Bg + (i << 10), Bs + (wv << 12) + (i << 10));
    }
  }
  __syncthreads();

  // ---- MFMA: 4 k-steps of 32 (fp8), 16 fragments per wave --------------------
  f32x4 acc[4][4];
#pragma unroll
  for (int m = 0; m < 4; ++m)
#pragma unroll
    for (int n = 0; n < 4; ++n)
      acc[m][n] = (f32x4){0.f, 0.f, 0.f, 0.f};

#pragma unroll
  for (int ks = 0; ks < 4; ++ks) {
    const int uf = (ks << 1) + (kq >> 1);          // logical 16B unit of this frag
    const int hb = (kq & 1) << 3;                  // 8B half within the unit
    long a[4], b[4];
#pragma unroll
    for (int m = 0; m < 4; ++m) {
      const int row = (wr << 6) + (m << 4) + lr;
      const int off = (row << 7) + ((uf ^ (lr & 7)) << 4) + hb;
      a[m] = *reinterpret_cast<const long*>(As + off);
    }
#pragma unroll
    for (int n = 0; n < 4; ++n) {
      const int row = (wc << 6) + (n << 4) + lr;
      const int off = (row << 7) + ((uf ^ (lr & 7)) << 4) + hb;
      b[n] = *reinterpret_cast<const long*>(Bs + off);
    }
#pragma unroll
    for (int m = 0; m < 4; ++m)
#pragma unroll
      for (int n = 0; n < 4; ++n)
        acc[m][n] = __builtin_amdgcn_mfma_f32_16x16x32_fp8_fp8(a[m], b[n], acc[m][n], 0, 0, 0);
  }

  // ---- epilogue: wave-level underflow skip, then exp2 ------------------------
  const bool diagblk = (q < 2) && (bx == by);
  f32x4 ax[4];
  float cy[4];
#pragma unroll
  for (int m = 0; m < 4; ++m)
    ax[m] = *reinterpret_cast<const f32x4*>(knA + R0 + (wr << 6) + (m << 4) + (kq << 2));
#pragma unroll
  for (int n = 0; n < 4; ++n)
    cy[n] = knB[C0 + (wc << 6) + (n << 4) + lr];

  f32x4 vm = acc[0][0];
#pragma unroll
  for (int m = 0; m < 4; ++m)
#pragma unroll
    for (int n = 0; n < 4; ++n) {
      if (m == 0 && n == 0) continue;
      vm[0] = fmaxf(vm[0], acc[m][n][0]);
      vm[1] = fmaxf(vm[1], acc[m][n][1]);
      vm[2] = fmaxf(vm[2], acc[m][n][2]);
      vm[3] = fmaxf(vm[3], acc[m][n][3]);
    }
  float amax = fmaxf(fmaxf(vm[0], vm[1]), fmaxf(vm[2], vm[3]));
  float axm = -1e30f;
#pragma unroll
  for (int m = 0; m < 4; ++m)
    axm = fmaxf(axm, fmaxf(fmaxf(ax[m][0], ax[m][1]), fmaxf(ax[m][2], ax[m][3])));
  float cym = fmaxf(fmaxf(cy[0], cy[1]), fmaxf(cy[2], cy[3]));
  float bound = fmaf(amax, C_2K, axm + cym);

  float local = 0.f;
  if (__any(bound > SKIP_BOUND)) {
    float l0 = 0.f, l1 = 0.f, l2 = 0.f, l3 = 0.f;
#pragma unroll
    for (int m = 0; m < 4; ++m) {
      const int rbase = (wr << 6) + (m << 4) + (kq << 2);
#pragma unroll
      for (int n = 0; n < 4; ++n) {
        const float e0 = __builtin_amdgcn_exp2f(fmaf(acc[m][n][0], C_2K, ax[m][0] + cy[n]));
        const float e1 = __builtin_amdgcn_exp2f(fmaf(acc[m][n][1], C_2K, ax[m][1] + cy[n]));
        const float e2 = __builtin_amdgcn_exp2f(fmaf(acc[m][n][2], C_2K, ax[m][2] + cy[n]));
        const float e3 = __builtin_amdgcn_exp2f(fmaf(acc[m][n][3], C_2K, ax[m][3] + cy[n]));
        if (diagblk) {
          const int cc = (wc << 6) + (n << 4) + lr;
          if (rbase + 0 != cc) l0 += e0;
          if (rbase + 1 != cc) l1 += e1;
          if (rbase + 2 != cc) l2 += e2;
          if (rbase + 3 != cc) l3 += e3;
        } else {
          l0 += e0; l1 += e1; l2 += e2; l3 += e3;
        }
      }
    }
    local = (l0 + l1) + (l2 + l3);
#pragma unroll
    for (int off = 32; off > 0; off >>= 1) local += __shfl_xor(local, off);
  }

  if (lane == 0) red[wv] = local;
  __syncthreads();
  if (threadIdx.x == 0) {
    float s = (red[0] + red[1]) + (red[2] + red[3]);
    float w;
    if (q < 2) w = ((bx == by) ? 1.f : 2.f) * (1.0f / 16773120.0f);  // alpha
    else       w = -2.0f / 16777216.0f;                               // -2*beta
    partials[t] = s * w;
  }
}

// ---- deterministic final reduction ------------------------------------------
__global__ __launch_bounds__(256) void mmd_final(const float* __restrict__ partials,
                                                 float* __restrict__ out) {
  float v = 0.f;
  for (int i = threadIdx.x; i < NBLK; i += 256) v += partials[i];
#pragma unroll
  for (int off = 32; off > 0; off >>= 1) v += __shfl_xor(v, off);
  __shared__ float red[4];
  if ((threadIdx.x & 63) == 0) red[threadIdx.x >> 6] = v;
  __syncthreads();
  if (threadIdx.x == 0) {
    // analytic diagonal: n*(alpha1+alpha2) = 2/4095
    out[0] = ((red[0] + red[1]) + (red[2] + red[3])) + (float)(2.0 / 4095.0);
  }
}

extern "C" void kernel_launch(void* const* d_in, const int* in_sizes, int n_in,
                              void* d_out, int out_size, void* d_ws, size_t ws_size,
                              hipStream_t stream) {
  const float* X = (const float*)d_in[0];
  const float* Y = (const float*)d_in[1];
  float* kn       = (float*)d_ws;                       // 8192 floats (-K*norm^2)
  float* partials = kn + 8192;                          // 2080 floats
  unsigned char* Xq = (unsigned char*)(partials + 2080);   // 4096*128 fp8 (16B-aligned)
  unsigned char* Yq = Xq + (size_t)Nn * 128;
  float* out = (float*)d_out;

  hipLaunchKernelGGL(prep_kernel, dim3(2048), dim3(256), 0, stream, X, Y, kn, Xq, Yq);
  hipLaunchKernelGGL(mmd_main, dim3(NBLK), dim3(256), 0, stream, Xq, Yq, kn, partials);
  hipLaunchKernelGGL(mmd_final, dim3(1), dim3(256), 0, stream, partials, out);
}